// Round 14
// baseline (329.326 us; speedup 1.0000x reference)
//
#include <hip/hip_runtime.h>
#include <hip/hip_bf16.h>
#include <stdint.h>

#define S_LEN   2048
#define BATCH   2
#define HID     2048
#define NHEADS  16
#define HDIM    128
#define ROWS    (BATCH * S_LEN)          // 4096
#define QKS     4096                     // qk row stride (2*HID; V lives in VT)
#define ATT_SCALE 0.08838834764831843f   // 1/sqrt(128)
#define LOG2E     1.4426950408889634f

typedef __attribute__((ext_vector_type(8))) short s16x8;
typedef __attribute__((ext_vector_type(4))) float f32x4;

#define GLL16(gp, lp)                                                          \
  __builtin_amdgcn_global_load_lds(                                            \
      (__attribute__((address_space(1))) void*)(gp),                           \
      (__attribute__((address_space(3))) void*)(lp), 16, 0, 0)

__device__ __forceinline__ float bf2f(unsigned short u) {
  union { unsigned int i; float f; } v; v.i = ((unsigned int)u) << 16; return v.f;
}
__device__ __forceinline__ unsigned short f2bf(float f) {
  union { float f; unsigned int i; } v; v.f = f;
  unsigned int i = v.i;
  return (unsigned short)((i + 0x7FFFu + ((i >> 16) & 1u)) >> 16);
}
__device__ __forceinline__ void store_out(unsigned short* p, float v) { *p = f2bf(v); }
__device__ __forceinline__ void store_out(float* p, float v) { *p = v; }

// ---------------- fused weight cast fp32 -> bf16 (4 weights, 1 launch) ----------------
__global__ __launch_bounds__(256) void cast4_kernel(const float* __restrict__ w0,
                                                    const float* __restrict__ w1,
                                                    const float* __restrict__ w2,
                                                    const float* __restrict__ w3,
                                                    unsigned short* __restrict__ dqkv,
                                                    unsigned short* __restrict__ dwo) {
  const int which = blockIdx.y;
  const float* src = (which == 0) ? w0 : (which == 1) ? w1 : (which == 2) ? w2 : w3;
  unsigned short* dst = (which < 3) ? dqkv + (size_t)which * HID * HID : dwo;
  int i = blockIdx.x * 256 + threadIdx.x;
  float4 v = ((const float4*)src)[i];
  ushort4 o;
  o.x = f2bf(v.x); o.y = f2bf(v.y); o.z = f2bf(v.z); o.w = f2bf(v.w);
  ((ushort4*)dst)[i] = o;
}

// ---------------- RMSNorm (fp32 in, bf16 out) ----------------
__global__ __launch_bounds__(256) void rmsnorm_kernel(const float* __restrict__ x,
                                                      const float* __restrict__ w,
                                                      unsigned short* __restrict__ h) {
  int row = blockIdx.x;
  int t = threadIdx.x;
  const float4* xr4 = (const float4*)(x + (size_t)row * HID);
  float4 a = xr4[t], b = xr4[t + 256];
  float ss = a.x*a.x + a.y*a.y + a.z*a.z + a.w*a.w
           + b.x*b.x + b.y*b.y + b.z*b.z + b.w*b.w;
#pragma unroll
  for (int off = 32; off >= 1; off >>= 1) ss += __shfl_xor(ss, off, 64);
  __shared__ float red[4];
  if ((t & 63) == 0) red[t >> 6] = ss;
  __syncthreads();
  float tot = red[0] + red[1] + red[2] + red[3];
  float rs = rsqrtf(tot * (1.0f / (float)HID) + 1e-6f);
  const float4* w4 = (const float4*)w;
  float4 wa = w4[t], wb = w4[t + 256];
  ushort4 oa, ob;
  oa.x = f2bf(a.x * wa.x * rs); oa.y = f2bf(a.y * wa.y * rs);
  oa.z = f2bf(a.z * wa.z * rs); oa.w = f2bf(a.w * wa.w * rs);
  ob.x = f2bf(b.x * wb.x * rs); ob.y = f2bf(b.y * wb.y * rs);
  ob.z = f2bf(b.z * wb.z * rs); ob.w = f2bf(b.w * wb.w * rs);
  ushort4* hr = (ushort4*)(h + (size_t)row * HID);
  hr[t] = oa; hr[t + 256] = ob;
}

// ---------------- RoPE tables ----------------
__global__ void rope_tab_kernel(float* __restrict__ cost, float* __restrict__ sint) {
  int s = blockIdx.x, j = threadIdx.x;  // 64 threads
  float inv = powf(10000.0f, -((float)j) / 64.0f);
  float ang = (float)s * inv;
  cost[s * 64 + j] = cosf(ang);
  sint[s * 64 + j] = sinf(ang);
}

// ---------------- RoPE apply in-place on q,k (qk buffer, stride QKS) ----------------
// q pre-scaled by ATT_SCALE*log2(e): attention softmax runs in the exp2 domain.
__global__ __launch_bounds__(256) void rope_kernel(const int* __restrict__ pos_ids,
                                                   const float* __restrict__ cost,
                                                   const float* __restrict__ sint,
                                                   unsigned short* __restrict__ qk) {
  int row = blockIdx.x;            // b*S + s
  int p = pos_ids[row];
  int t = threadIdx.x;
  int head = t >> 4;
  int j0 = (t & 15) * 4;
  size_t base = (size_t)row * QKS + head * HDIM;
  float4 c = *(const float4*)(cost + p * 64 + j0);
  float4 s = *(const float4*)(sint + p * 64 + j0);
#pragma unroll
  for (int which = 0; which < 2; which++) {
    unsigned short* ptr = qk + base + which * HID;  // q then k
    float sc = which ? 1.0f : (ATT_SCALE * LOG2E);
    ushort4 v1 = *(ushort4*)(ptr + j0);
    ushort4 v2 = *(ushort4*)(ptr + 64 + j0);
    ushort4 o1, o2;
    o1.x = f2bf((bf2f(v1.x) * c.x - bf2f(v2.x) * s.x) * sc);
    o1.y = f2bf((bf2f(v1.y) * c.y - bf2f(v2.y) * s.y) * sc);
    o1.z = f2bf((bf2f(v1.z) * c.z - bf2f(v2.z) * s.z) * sc);
    o1.w = f2bf((bf2f(v1.w) * c.w - bf2f(v2.w) * s.w) * sc);
    o2.x = f2bf((bf2f(v2.x) * c.x + bf2f(v1.x) * s.x) * sc);
    o2.y = f2bf((bf2f(v2.y) * c.y + bf2f(v1.y) * s.y) * sc);
    o2.z = f2bf((bf2f(v2.z) * c.z + bf2f(v1.z) * s.z) * sc);
    o2.w = f2bf((bf2f(v2.w) * c.w + bf2f(v1.w) * s.w) * sc);
    *(ushort4*)(ptr + j0) = o1;
    *(ushort4*)(ptr + 64 + j0) = o2;
  }
}

// ---------------- 256x256 kk-half-staggered GEMM (QK projection) ----------------
#define SH(kt, bi, kk2) {                                                      \
    const unsigned short* sa_ = aQ + (size_t)(kt) * 64 + (kk2) * 32;           \
    const unsigned short* sb_ = bQ + (size_t)(kt) * 64 + (kk2) * 32;           \
    char* da_ = qsm + ((bi) * 2 + (kk2)) * 32768 + tid * 16;                   \
    GLL16(sa_, da_);                                                           \
    GLL16(sa_ + (size_t)128 * K, da_ + 8192);                                  \
    GLL16(sb_, da_ + 16384);                                                   \
    GLL16(sb_ + (size_t)128 * K, da_ + 16384 + 8192);                          \
  }

__global__ __launch_bounds__(512, 2) void gemm_qk_kernel(const unsigned short* __restrict__ A,
                                                         const unsigned short* __restrict__ B,
                                                         unsigned short* __restrict__ C,
                                                         int K, int N) {
  __shared__ __align__(16) unsigned short Qsm[2][2][2][256 * 32];  // 128 KB
  const int bm = blockIdx.y, bn = blockIdx.x;
  const int tid = threadIdx.x;
  const int w = tid >> 6, wr = w >> 2, wc = w & 3;
  const int l = tid & 63, g = l >> 4, r = l & 15;
  const int KT = K >> 6;

  const int srow = tid >> 2;
  const int sg = (tid & 3) ^ ((tid >> 2) & 3) ^ ((tid >> 4) & 3);
  const unsigned short* aQ = A + (size_t)(bm * 256 + srow) * K + sg * 8;
  const unsigned short* bQ = B + (size_t)(bn * 256 + srow) * K + sg * 8;
  char* const qsm = (char*)Qsm;

  f32x4 zero = {0.f, 0.f, 0.f, 0.f};
  f32x4 acc[8][4];
#pragma unroll
  for (int mi = 0; mi < 8; mi++)
#pragma unroll
    for (int ni = 0; ni < 4; ni++) acc[mi][ni] = zero;

  const int ro = ((g ^ (r & 3) ^ ((r >> 2) & 3)) << 4);
  const int aOff = (wr * 128 + r) * 64 + ro;           // + mi*1024
  const int bOff = 16384 + (wc * 64 + r) * 64 + ro;    // + ni*1024

  SH(0, 0, 0); SH(0, 0, 1);

  for (int kt = 0; kt < KT; ++kt) {
    const int buf = kt & 1;
    const bool more = (kt + 1 < KT);
    const char* l0 = qsm + (buf * 2 + 0) * 32768;
    const char* l1 = qsm + (buf * 2 + 1) * 32768;

    asm volatile("s_waitcnt vmcnt(4)" ::: "memory");
    __builtin_amdgcn_s_barrier();
    __builtin_amdgcn_sched_barrier(0);
    s16x8 a[4], b[4];
#pragma unroll
    for (int ni = 0; ni < 4; ni++) b[ni] = *(const s16x8*)(l0 + bOff + ni * 1024);
#pragma unroll
    for (int i = 0; i < 4; i++) a[i] = *(const s16x8*)(l0 + aOff + i * 1024);
    if (more) SH(kt + 1, buf ^ 1, 0);
    __builtin_amdgcn_s_setprio(1);
#pragma unroll
    for (int ni = 0; ni < 4; ni++)
#pragma unroll
      for (int i = 0; i < 4; i++)
        acc[i][ni] = __builtin_amdgcn_mfma_f32_16x16x32_bf16(a[i], b[ni], acc[i][ni], 0, 0, 0);
    __builtin_amdgcn_s_setprio(0);

    s16x8 a2[4];
#pragma unroll
    for (int i = 0; i < 4; i++) a2[i] = *(const s16x8*)(l0 + aOff + (4 + i) * 1024);
    __builtin_amdgcn_s_setprio(1);
#pragma unroll
    for (int ni = 0; ni < 4; ni++)
#pragma unroll
      for (int i = 0; i < 4; i++)
        acc[4 + i][ni] = __builtin_amdgcn_mfma_f32_16x16x32_bf16(a2[i], b[ni], acc[4 + i][ni], 0, 0, 0);
    __builtin_amdgcn_s_setprio(0);

    if (more) { asm volatile("s_waitcnt vmcnt(4)" ::: "memory"); }
    else      { asm volatile("s_waitcnt vmcnt(0)" ::: "memory"); }
    __builtin_amdgcn_s_barrier();
    __builtin_amdgcn_sched_barrier(0);
#pragma unroll
    for (int ni = 0; ni < 4; ni++) b[ni] = *(const s16x8*)(l1 + bOff + ni * 1024);
#pragma unroll
    for (int i = 0; i < 4; i++) a[i] = *(const s16x8*)(l1 + aOff + i * 1024);
    if (more) SH(kt + 1, buf ^ 1, 1);
    __builtin_amdgcn_s_setprio(1);
#pragma unroll
    for (int ni = 0; ni < 4; ni++)
#pragma unroll
      for (int i = 0; i < 4; i++)
        acc[i][ni] = __builtin_amdgcn_mfma_f32_16x16x32_bf16(a[i], b[ni], acc[i][ni], 0, 0, 0);
    __builtin_amdgcn_s_setprio(0);

#pragma unroll
    for (int i = 0; i < 4; i++) a2[i] = *(const s16x8*)(l1 + aOff + (4 + i) * 1024);
    __builtin_amdgcn_s_setprio(1);
#pragma unroll
    for (int ni = 0; ni < 4; ni++)
#pragma unroll
      for (int i = 0; i < 4; i++)
        acc[4 + i][ni] = __builtin_amdgcn_mfma_f32_16x16x32_bf16(a2[i], b[ni], acc[4 + i][ni], 0, 0, 0);
    __builtin_amdgcn_s_setprio(0);
  }

#pragma unroll
  for (int mi = 0; mi < 8; mi++)
#pragma unroll
    for (int ni = 0; ni < 4; ni++) {
      const int crow = bm * 256 + wr * 128 + mi * 16 + g * 4;
      const int ccol = bn * 256 + wc * 64 + ni * 16 + r;
#pragma unroll
      for (int j = 0; j < 4; j++)
        store_out(&C[(size_t)(crow + j) * N + ccol], acc[mi][ni][j]);
    }
}
#undef SH

// ---------------- Triple-buffered counted-vmcnt GEMM ----------------
// VT_OUT: write C transposed into VT layout [bh*128+d][S_LEN] (V projection).
#define SA(kt, bi) {                                                           \
    const unsigned short* s_ = aS + (size_t)(kt) * 64;                         \
    char* d_ = (char*)Ab[bi] + tid * 16;                                       \
    GLL16(s_, d_);                                                             \
    GLL16(s_ + (size_t)64 * K, d_ + 8192);                                     \
  }
#define SB(kt, bi, hf) {                                                       \
    const unsigned short* s_ = bS + (size_t)(hf) * 128 * K + (size_t)(kt) * 64;\
    char* d_ = (char*)Bb[bi] + (hf) * 16384 + tid * 16;                        \
    GLL16(s_, d_);                                                             \
    GLL16(s_ + (size_t)64 * K, d_ + 8192);                                     \
  }

template <typename OutT, int NI, bool VT_OUT>
__global__ __launch_bounds__(512, 1) void gemm8_kernel(const unsigned short* __restrict__ A,
                                                       const unsigned short* __restrict__ B,
                                                       OutT* __restrict__ C, int K, int N) {
  __shared__ __align__(16) unsigned short Ab[3][128 * 64];       // 48 KB
  __shared__ __align__(16) unsigned short Bb[3][NI * 64 * 64];   // 96 or 48 KB
  const int bm = blockIdx.y, bn = blockIdx.x;                    // plain mapping
  const int tid = threadIdx.x;
  const int w = tid >> 6, wr = w >> 2, wc = w & 3;
  const int l = tid & 63, g = l >> 4, r = l & 15;
  const int KT = K >> 6;

  const int srow = tid >> 3;
  const int sgr = (tid & 7) ^ (srow & 7);
  const unsigned short* aS = A + (size_t)(bm * 128 + srow) * K + sgr * 8;
  const unsigned short* bS = B + (size_t)(bn * (NI * 64) + srow) * K + sgr * 8;

  f32x4 zero = {0.f, 0.f, 0.f, 0.f};
  f32x4 acc[4][NI];
#pragma unroll
  for (int mi = 0; mi < 4; mi++)
#pragma unroll
    for (int ni = 0; ni < NI; ni++) acc[mi][ni] = zero;

  const int swx = (r & 7) << 4;
  const int ks0 = (g << 4) ^ swx;
  const int ks1 = ((4 | g) << 4) ^ swx;
  const int aOff = (wr * 64 + r) * 128;
  const int bOff = (wc * (NI * 16) + r) * 128;

  SA(0, 0); SB(0, 0, 0); if (NI == 4) SB(0, 0, 1);
  SA(1, 1); SB(1, 1, 0); if (NI == 4) SB(1, 1, 1);

  int cur = 0;
  for (int kt = 0; kt < KT; ++kt) {
    const int b2 = (cur >= 1) ? cur - 1 : cur + 2;   // (cur+2)%3
    if (kt == KT - 1)      { asm volatile("s_waitcnt vmcnt(0)" ::: "memory"); }
    else if (NI == 4)      { asm volatile("s_waitcnt vmcnt(6)" ::: "memory"); }
    else                   { asm volatile("s_waitcnt vmcnt(4)" ::: "memory"); }
    __builtin_amdgcn_s_barrier();
    __builtin_amdgcn_sched_barrier(0);
    const char* lA = (const char*)Ab[cur];
    const char* lB = (const char*)Bb[cur];
    const bool more = (kt + 2 < KT);

    s16x8 a[4][2], b[NI][2];
#pragma unroll
    for (int mi = 0; mi < 4; mi++) {
      a[mi][0] = *(const s16x8*)(lA + aOff + mi * 2048 + ks0);
      a[mi][1] = *(const s16x8*)(lA + aOff + mi * 2048 + ks1);
    }
#pragma unroll
    for (int ni = 0; ni < NI / 2; ni++) {
      b[ni][0] = *(const s16x8*)(lB + bOff + ni * 2048 + ks0);
      b[ni][1] = *(const s16x8*)(lB + bOff + ni * 2048 + ks1);
    }
    if (more) { SA(kt + 2, b2); if (NI == 4) SB(kt + 2, b2, 0); }
    __builtin_amdgcn_s_setprio(1);
#pragma unroll
    for (int kk = 0; kk < 2; kk++)
#pragma unroll
      for (int ni = 0; ni < NI / 2; ni++)
#pragma unroll
        for (int mi = 0; mi < 4; mi++)
          acc[mi][ni] = __builtin_amdgcn_mfma_f32_16x16x32_bf16(a[mi][kk], b[ni][kk], acc[mi][ni], 0, 0, 0);
    __builtin_amdgcn_s_setprio(0);
    __builtin_amdgcn_sched_barrier(0);

#pragma unroll
    for (int ni = NI / 2; ni < NI; ni++) {
      b[ni][0] = *(const s16x8*)(lB + bOff + ni * 2048 + ks0);
      b[ni][1] = *(const s16x8*)(lB + bOff + ni * 2048 + ks1);
    }
    if (more) { if (NI == 4) { SB(kt + 2, b2, 1); } else { SB(kt + 2, b2, 0); } }
    __builtin_amdgcn_s_setprio(1);
#pragma unroll
    for (int kk = 0; kk < 2; kk++)
#pragma unroll
      for (int ni = NI / 2; ni < NI; ni++)
#pragma unroll
        for (int mi = 0; mi < 4; mi++)
          acc[mi][ni] = __builtin_amdgcn_mfma_f32_16x16x32_bf16(a[mi][kk], b[ni][kk], acc[mi][ni], 0, 0, 0);
    __builtin_amdgcn_s_setprio(0);
    cur = (cur == 2) ? 0 : cur + 1;
  }

#pragma unroll
  for (int mi = 0; mi < 4; mi++)
#pragma unroll
    for (int ni = 0; ni < NI; ni++) {
      const int crow = bm * 128 + wr * 64 + mi * 16 + g * 4;
      const int ccol = bn * (NI * 64) + wc * (NI * 16) + ni * 16 + r;
      if constexpr (VT_OUT) {
        // C^T into VT[(b*16+head)*128 + d][s]; 4 consecutive tokens -> ushort4
        const int bidx = crow >> 11;            // token / S_LEN
        const int s0 = crow & (S_LEN - 1);
        const int vrow = (bidx * 16 + (ccol >> 7)) * 128 + (ccol & 127);
        ushort4 o;
        o.x = f2bf(acc[mi][ni][0]); o.y = f2bf(acc[mi][ni][1]);
        o.z = f2bf(acc[mi][ni][2]); o.w = f2bf(acc[mi][ni][3]);
        *(ushort4*)((unsigned short*)C + (size_t)vrow * S_LEN + s0) = o;
      } else {
#pragma unroll
        for (int j = 0; j < 4; j++)
          store_out(&C[(size_t)(crow + j) * N + ccol], acc[mi][ni][j]);
      }
    }
}

// ---------------- Flash attention, causal, swapped-operand softmax ----------------
// 1024 blocks x 256 thr (4 waves); block = one 64-row q-tile; LPT heavy-first
// + XCD chunking (r7-proven mapping). K double-buffered in LDS (32KB); V^T read
// DIRECTLY from global (L2-resident via XCD chunk) into registers at tile top
// -- issue-to-use distance covers L2 latency, deletes VT staging. LDS 40KB ->
// 4 blocks/CU by LDS (VGPR ~150 -> 3 waves/SIMD, +50% TLP vs r13's 2).
// QK as mfma(K,Q): lane holds S^T[kv][q=r]; exp2 domain, defer-max THR=8,
// cvt_pk P->LDS b64, PV = mfma(V^T,P^T), lane-partial l reduced in epilogue.
__global__ __launch_bounds__(256) void attn_kernel(const unsigned short* __restrict__ QK,
                                                   const unsigned short* __restrict__ VT,
                                                   unsigned short* __restrict__ O) {
  __shared__ __align__(16) unsigned short Ksm[2][64 * 128];    // 32KB swizzled
  __shared__ __align__(16) unsigned short Psm[4 * 16 * 64];    // 8KB per-wave [q][kv]
  const int bid = blockIdx.x;
  const int grp = bid & 7, idx = bid >> 3;     // idx 0..127
  const int qt = 31 - (idx >> 2);              // heavy-first (LPT)
  const int bh = (grp << 2) | (idx & 3);
  const int b = bh >> 4, hd = bh & 15;
  const int tid = threadIdx.x, w = tid >> 6, l = tid & 63, g = l >> 4, r = l & 15;
  const int qbs = qt * 64 + w * 16;            // wave's q-row base (16 rows)

  // Q fragment (B operand): lane row = q = qbs + r (pre-scaled by scale*log2e)
  const unsigned short* qp = QK + (size_t)(b * S_LEN + qbs + r) * QKS + hd * HDIM;
  s16x8 qf[4];
#pragma unroll
  for (int ks = 0; ks < 4; ks++) qf[ks] = *(const s16x8*)(qp + ks * 32 + g * 8);

  float mreg = -1e30f, lregp = 0.f;            // lane-partial l
  f32x4 zero = {0.f, 0.f, 0.f, 0.f};
  f32x4 oacc[8];                               // O^T[d=di*16+g*4+jj][q=r]
#pragma unroll
  for (int di = 0; di < 8; di++) oacc[di] = zero;

  const int cK = tid & 15, rowK = tid >> 4;            // 0..15 (+16/i)
  const unsigned short* kp_base = QK + (size_t)(b * S_LEN + rowK) * QKS + HID + hd * HDIM
                                  + ((cK ^ (rowK & 7)) << 3);
  // per-lane V^T base: row = bh*128 + r (+di*16), 16B granule by g (+ksl*32)
  const unsigned short* vgp = VT + (size_t)(bh * 128 + r) * S_LEN + g * 8;
  char* const ksm0 = (char*)Ksm;
  char* const psm_w = (char*)Psm + w * 2048;
  const int pswz = (r & 7) << 4;

#define STAGE(kt, bufi)                                                        \
  {                                                                            \
    const unsigned short* kp_ = kp_base + (size_t)((kt) * 64) * QKS;           \
    char* kd_ = ksm0 + (bufi) * 16384;                                         \
    GLL16(kp_,                      kd_ + tid * 16);                           \
    GLL16(kp_ + (size_t)16 * QKS,   kd_ + (tid + 256) * 16);                   \
    GLL16(kp_ + (size_t)32 * QKS,   kd_ + (tid + 512) * 16);                   \
    GLL16(kp_ + (size_t)48 * QKS,   kd_ + (tid + 768) * 16);                   \
  }

  const int nt = qt + 1;
  STAGE(0, 0);

  for (int kt2 = 0; kt2 < nt; kt2++) {
    const int buf = kt2 & 1;
    asm volatile("s_waitcnt vmcnt(0)" ::: "memory");
    __builtin_amdgcn_s_barrier();
    __builtin_amdgcn_sched_barrier(0);
    if (kt2 + 1 < nt) STAGE(kt2 + 1, buf ^ 1);   // K loads fly under this tile

    // V fragments for THIS tile: 16 independent global loads (L2-resident via
    // XCD chunking), issued here so ~full-tile latency hiding before PV.
    const unsigned short* vrow = vgp + kt2 * 64;
    s16x8 vfr[2][8];
#pragma unroll
    for (int ksl = 0; ksl < 2; ksl++)
#pragma unroll
      for (int di = 0; di < 8; di++)
        vfr[ksl][di] = *(const s16x8*)(vrow + (size_t)di * 16 * S_LEN + ksl * 32);

    const char* ksm_c = ksm0 + buf * 16384;

    // S^T = K Q^T: sacc[ni][jj] = S[kv=kt2*64+ni*16+g*4+jj][q=qbs+r]
    f32x4 sacc[4];
#pragma unroll
    for (int ni = 0; ni < 4; ni++) sacc[ni] = zero;
#pragma unroll
    for (int ni = 0; ni < 4; ni++) {
      const int krow = ni * 16 + r;
      const int swz = (krow & 7) << 4;
      const char* kb2 = ksm_c + krow * 256;
#pragma unroll
      for (int ks = 0; ks < 4; ks++) {
        s16x8 kf = *(const s16x8*)(kb2 + ((ks * 64 + g * 16) ^ swz));
        sacc[ni] = __builtin_amdgcn_mfma_f32_16x16x32_bf16(kf, qf[ks], sacc[ni], 0, 0, 0);
      }
    }

    // causal mask (diagonal tile only)
    if (kt2 == qt) {
#pragma unroll
      for (int ni = 0; ni < 4; ni++)
#pragma unroll
        for (int jj = 0; jj < 4; jj++)
          if ((kt2 * 64 + ni * 16 + g * 4 + jj) > (qbs + r)) sacc[ni][jj] = -1e30f;
    }

    // row max for q=r: local 16-tree + 2 shfl (over g lanes)
    float m0 = fmaxf(fmaxf(sacc[0][0], sacc[0][1]), fmaxf(sacc[0][2], sacc[0][3]));
    float m1 = fmaxf(fmaxf(sacc[1][0], sacc[1][1]), fmaxf(sacc[1][2], sacc[1][3]));
    float m2 = fmaxf(fmaxf(sacc[2][0], sacc[2][1]), fmaxf(sacc[2][2], sacc[2][3]));
    float m3 = fmaxf(fmaxf(sacc[3][0], sacc[3][1]), fmaxf(sacc[3][2], sacc[3][3]));
    float mx = fmaxf(fmaxf(m0, m1), fmaxf(m2, m3));
    mx = fmaxf(mx, __shfl_xor(mx, 16, 64));
    mx = fmaxf(mx, __shfl_xor(mx, 32, 64));

    // defer-max (THR=8 in log2 units)
    if (__any(mx > mreg + 8.0f)) {
      float mn = fmaxf(mreg, mx);
      float corr = exp2f(mreg - mn);
      mreg = mn;
      lregp *= corr;
#pragma unroll
      for (int di = 0; di < 8; di++) oacc[di] = oacc[di] * corr;
    }

    // exp + lane-partial sum
#pragma unroll
    for (int ni = 0; ni < 4; ni++)
#pragma unroll
      for (int jj = 0; jj < 4; jj++) sacc[ni][jj] = exp2f(sacc[ni][jj] - mreg);
    float s0 = (sacc[0][0] + sacc[0][1]) + (sacc[0][2] + sacc[0][3]);
    float s1 = (sacc[1][0] + sacc[1][1]) + (sacc[1][2] + sacc[1][3]);
    float s2 = (sacc[2][0] + sacc[2][1]) + (sacc[2][2] + sacc[2][3]);
    float s3 = (sacc[3][0] + sacc[3][1]) + (sacc[3][2] + sacc[3][3]);
    lregp += (s0 + s1) + (s2 + s3);

    // P -> wave-private LDS [q=r][kv], swizzled; kv-pairs packed -> b64 writes
#pragma unroll
    for (int ni = 0; ni < 4; ni++) {
      unsigned int pk01, pk23;
      asm("v_cvt_pk_bf16_f32 %0, %1, %2" : "=v"(pk01) : "v"(sacc[ni][0]), "v"(sacc[ni][1]));
      asm("v_cvt_pk_bf16_f32 %0, %1, %2" : "=v"(pk23) : "v"(sacc[ni][2]), "v"(sacc[ni][3]));
      uint2 pk; pk.x = pk01; pk.y = pk23;
      *(uint2*)(psm_w + ((r * 128 + ni * 32 + g * 8) ^ pswz)) = pk;
    }

    // PV: O^T += V^T * P^T; A = V^T frag (registers), B = P^T frag (row q=r)
#pragma unroll
    for (int ksl = 0; ksl < 2; ksl++) {
      s16x8 pb = *(const s16x8*)(psm_w + ((r * 128 + ksl * 64 + g * 16) ^ pswz));
#pragma unroll
      for (int di = 0; di < 8; di++)
        oacc[di] = __builtin_amdgcn_mfma_f32_16x16x32_bf16(vfr[ksl][di], pb, oacc[di], 0, 0, 0);
    }
  }
#undef STAGE

  // epilogue: reduce l across g lanes; O[q=qbs+r][d], 8B stores
  float lsum = lregp;
  lsum += __shfl_xor(lsum, 16, 64);
  lsum += __shfl_xor(lsum, 32, 64);
  const float inv = 1.0f / lsum;
  unsigned short* orow = O + (size_t)(b * S_LEN + qbs + r) * HID + hd * HDIM;
#pragma unroll
  for (int di = 0; di < 8; di++) {
    ushort4 o;
    o.x = f2bf(oacc[di][0] * inv); o.y = f2bf(oacc[di][1] * inv);
    o.z = f2bf(oacc[di][2] * inv); o.w = f2bf(oacc[di][3] * inv);
    *(ushort4*)(orow + di * 16 + g * 4) = o;
  }
}

extern "C" void kernel_launch(void* const* d_in, const int* in_sizes, int n_in,
                              void* d_out, int out_size, void* d_ws, size_t ws_size,
                              hipStream_t stream) {
  const float* x      = (const float*)d_in[0];
  const float* norm_w = (const float*)d_in[1];
  const float* wq     = (const float*)d_in[2];
  const float* wk     = (const float*)d_in[3];
  const float* wv     = (const float*)d_in[4];
  const float* wo     = (const float*)d_in[5];
  const int*   pos    = (const int*)d_in[6];
  float* out = (float*)d_out;

  char* ws = (char*)d_ws;
  const size_t WQKV_B = (size_t)3 * HID * HID * 2;   // 24 MB
  const size_t WO_B   = (size_t)HID * HID * 2;       // 8 MB
  const size_t H_B    = (size_t)ROWS * HID * 2;      // 16 MB
  const size_t QK_B   = (size_t)ROWS * QKS * 2;      // 32 MB

  unsigned short* wqkvb = (unsigned short*)(ws);                     // [0,24)
  unsigned short* vt    = (unsigned short*)(ws);                     // aliases [0,16) after gemm_qk
  unsigned short* wob   = (unsigned short*)(ws + WQKV_B);            // [24,32)
  unsigned short* h     = (unsigned short*)(ws + WQKV_B + WO_B);     // [32,48) also ctx
  unsigned short* qk    = (unsigned short*)(ws + WQKV_B + WO_B + H_B);   // [48,80)
  float* cost = (float*)(ws + WQKV_B + WO_B + H_B + QK_B);
  float* sint = cost + (size_t)S_LEN * 64;

  dim3 cgrid(HID * HID / 4 / 256, 4);
  cast4_kernel<<<cgrid, 256, 0, stream>>>(wq, wk, wv, wo, wqkvb, wob);
  rope_tab_kernel<<<S_LEN, 64, 0, stream>>>(cost, sint);
  rmsnorm_kernel<<<ROWS, 256, 0, stream>>>(x, norm_w, h);

  // Q,K projection: 256x256-tile kernel, 16x16 = 256 blocks (1/CU, no tail)
  dim3 qkgrid(2 * HID / 256, ROWS / 256);
  gemm_qk_kernel<<<qkgrid, 512, 0, stream>>>(h, wqkvb, qk, HID, QKS);

  // V projection writes V^T directly (wq/wk region is dead after gemm_qk)
  dim3 vgrid(HID / 256, ROWS / 128);
  gemm8_kernel<unsigned short, 4, true><<<vgrid, 512, 0, stream>>>(
      h, wqkvb + (size_t)2 * HID * HID, vt, HID, S_LEN);

  rope_kernel<<<ROWS, 256, 0, stream>>>(pos, cost, sint, qk);

  attn_kernel<<<1024, 256, 0, stream>>>(qk, vt, h /* ctx */);

  // out-proj: gemm8 NI=4, 8x32 = 256 blocks
  dim3 ogrid(HID / 256, ROWS / 128);
  gemm8_kernel<float, 4, false><<<ogrid, 512, 0, stream>>>(h, wob, out, HID, HID);
}

// Round 15
// 255.731 us; speedup vs baseline: 1.2878x; 1.2878x over previous
//
#include <hip/hip_runtime.h>
#include <hip/hip_bf16.h>
#include <stdint.h>

#define S_LEN   2048
#define BATCH   2
#define HID     2048
#define NHEADS  16
#define HDIM    128
#define ROWS    (BATCH * S_LEN)          // 4096
#define QKS     4096                     // qk row stride (2*HID; V lives in VT)
#define ATT_SCALE 0.08838834764831843f   // 1/sqrt(128)
#define LOG2E     1.4426950408889634f
#define LOG2_10000 13.287712379549449f   // log2(10000)

typedef __attribute__((ext_vector_type(8))) short s16x8;
typedef __attribute__((ext_vector_type(4))) float f32x4;

#define GLL16(gp, lp)                                                          \
  __builtin_amdgcn_global_load_lds(                                            \
      (__attribute__((address_space(1))) void*)(gp),                           \
      (__attribute__((address_space(3))) void*)(lp), 16, 0, 0)

__device__ __forceinline__ float bf2f(unsigned short u) {
  union { unsigned int i; float f; } v; v.i = ((unsigned int)u) << 16; return v.f;
}
__device__ __forceinline__ unsigned short f2bf(float f) {
  union { float f; unsigned int i; } v; v.f = f;
  unsigned int i = v.i;
  return (unsigned short)((i + 0x7FFFu + ((i >> 16) & 1u)) >> 16);
}
__device__ __forceinline__ void store_out(unsigned short* p, float v) { *p = f2bf(v); }
__device__ __forceinline__ void store_out(float* p, float v) { *p = v; }

// ---------------- fused weight cast fp32 -> bf16 (4 weights, 1 launch) ----------------
__global__ __launch_bounds__(256) void cast4_kernel(const float* __restrict__ w0,
                                                    const float* __restrict__ w1,
                                                    const float* __restrict__ w2,
                                                    const float* __restrict__ w3,
                                                    unsigned short* __restrict__ dqkv,
                                                    unsigned short* __restrict__ dwo) {
  const int which = blockIdx.y;
  const float* src = (which == 0) ? w0 : (which == 1) ? w1 : (which == 2) ? w2 : w3;
  unsigned short* dst = (which < 3) ? dqkv + (size_t)which * HID * HID : dwo;
  int i = blockIdx.x * 256 + threadIdx.x;
  float4 v = ((const float4*)src)[i];
  ushort4 o;
  o.x = f2bf(v.x); o.y = f2bf(v.y); o.z = f2bf(v.z); o.w = f2bf(v.w);
  ((ushort4*)dst)[i] = o;
}

// ---------------- RMSNorm (fp32 in, bf16 out) ----------------
__global__ __launch_bounds__(256) void rmsnorm_kernel(const float* __restrict__ x,
                                                      const float* __restrict__ w,
                                                      unsigned short* __restrict__ h) {
  int row = blockIdx.x;
  int t = threadIdx.x;
  const float4* xr4 = (const float4*)(x + (size_t)row * HID);
  float4 a = xr4[t], b = xr4[t + 256];
  float ss = a.x*a.x + a.y*a.y + a.z*a.z + a.w*a.w
           + b.x*b.x + b.y*b.y + b.z*b.z + b.w*b.w;
#pragma unroll
  for (int off = 32; off >= 1; off >>= 1) ss += __shfl_xor(ss, off, 64);
  __shared__ float red[4];
  if ((t & 63) == 0) red[t >> 6] = ss;
  __syncthreads();
  float tot = red[0] + red[1] + red[2] + red[3];
  float rs = rsqrtf(tot * (1.0f / (float)HID) + 1e-6f);
  const float4* w4 = (const float4*)w;
  float4 wa = w4[t], wb = w4[t + 256];
  ushort4 oa, ob;
  oa.x = f2bf(a.x * wa.x * rs); oa.y = f2bf(a.y * wa.y * rs);
  oa.z = f2bf(a.z * wa.z * rs); oa.w = f2bf(a.w * wa.w * rs);
  ob.x = f2bf(b.x * wb.x * rs); ob.y = f2bf(b.y * wb.y * rs);
  ob.z = f2bf(b.z * wb.z * rs); ob.w = f2bf(b.w * wb.w * rs);
  ushort4* hr = (ushort4*)(h + (size_t)row * HID);
  hr[t] = oa; hr[t + 256] = ob;
}

// ---------------- RoPE tables (exp2f instead of powf; float2 store) ----------------
__global__ void rope_tab_kernel(float* __restrict__ tab) {
  int s = blockIdx.x, j = threadIdx.x;  // 64 threads
  float inv = exp2f(-((float)j) * (LOG2_10000 / 64.0f));
  float ang = (float)s * inv;
  float2 cs;
  __sincosf(ang, &cs.y, &cs.x);         // cs.x = cos, cs.y = sin
  *(float2*)(tab + (s * 64 + j) * 2) = cs;
}

// ---------------- RoPE apply in-place on q,k (qk buffer, stride QKS) ----------------
// q pre-scaled by ATT_SCALE*log2(e): attention softmax runs in the exp2 domain.
__global__ __launch_bounds__(256) void rope_kernel(const int* __restrict__ pos_ids,
                                                   const float* __restrict__ tab,
                                                   unsigned short* __restrict__ qk) {
  int row = blockIdx.x;            // b*S + s
  int p = pos_ids[row];
  int t = threadIdx.x;
  int head = t >> 4;
  int j0 = (t & 15) * 4;
  size_t base = (size_t)row * QKS + head * HDIM;
  float4 cs01 = *(const float4*)(tab + (p * 64 + j0) * 2);      // c0 s0 c1 s1
  float4 cs23 = *(const float4*)(tab + (p * 64 + j0 + 2) * 2);  // c2 s2 c3 s3
  float4 c = {cs01.x, cs01.z, cs23.x, cs23.z};
  float4 s = {cs01.y, cs01.w, cs23.y, cs23.w};
#pragma unroll
  for (int which = 0; which < 2; which++) {
    unsigned short* ptr = qk + base + which * HID;  // q then k
    float sc = which ? 1.0f : (ATT_SCALE * LOG2E);
    ushort4 v1 = *(ushort4*)(ptr + j0);
    ushort4 v2 = *(ushort4*)(ptr + 64 + j0);
    ushort4 o1, o2;
    o1.x = f2bf((bf2f(v1.x) * c.x - bf2f(v2.x) * s.x) * sc);
    o1.y = f2bf((bf2f(v1.y) * c.y - bf2f(v2.y) * s.y) * sc);
    o1.z = f2bf((bf2f(v1.z) * c.z - bf2f(v2.z) * s.z) * sc);
    o1.w = f2bf((bf2f(v1.w) * c.w - bf2f(v2.w) * s.w) * sc);
    o2.x = f2bf((bf2f(v2.x) * c.x + bf2f(v1.x) * s.x) * sc);
    o2.y = f2bf((bf2f(v2.y) * c.y + bf2f(v1.y) * s.y) * sc);
    o2.z = f2bf((bf2f(v2.z) * c.z + bf2f(v1.z) * s.z) * sc);
    o2.w = f2bf((bf2f(v2.w) * c.w + bf2f(v1.w) * s.w) * sc);
    *(ushort4*)(ptr + j0) = o1;
    *(ushort4*)(ptr + 64 + j0) = o2;
  }
}

// ---------------- 256x256 kk-half-staggered GEMM (QK projection) ----------------
#define SH(kt, bi, kk2) {                                                      \
    const unsigned short* sa_ = aQ + (size_t)(kt) * 64 + (kk2) * 32;           \
    const unsigned short* sb_ = bQ + (size_t)(kt) * 64 + (kk2) * 32;           \
    char* da_ = qsm + ((bi) * 2 + (kk2)) * 32768 + tid * 16;                   \
    GLL16(sa_, da_);                                                           \
    GLL16(sa_ + (size_t)128 * K, da_ + 8192);                                  \
    GLL16(sb_, da_ + 16384);                                                   \
    GLL16(sb_ + (size_t)128 * K, da_ + 16384 + 8192);                          \
  }

__global__ __launch_bounds__(512, 2) void gemm_qk_kernel(const unsigned short* __restrict__ A,
                                                         const unsigned short* __restrict__ B,
                                                         unsigned short* __restrict__ C,
                                                         int K, int N) {
  __shared__ __align__(16) unsigned short Qsm[2][2][2][256 * 32];  // 128 KB
  const int bm = blockIdx.y, bn = blockIdx.x;
  const int tid = threadIdx.x;
  const int w = tid >> 6, wr = w >> 2, wc = w & 3;
  const int l = tid & 63, g = l >> 4, r = l & 15;
  const int KT = K >> 6;

  const int srow = tid >> 2;
  const int sg = (tid & 3) ^ ((tid >> 2) & 3) ^ ((tid >> 4) & 3);
  const unsigned short* aQ = A + (size_t)(bm * 256 + srow) * K + sg * 8;
  const unsigned short* bQ = B + (size_t)(bn * 256 + srow) * K + sg * 8;
  char* const qsm = (char*)Qsm;

  f32x4 zero = {0.f, 0.f, 0.f, 0.f};
  f32x4 acc[8][4];
#pragma unroll
  for (int mi = 0; mi < 8; mi++)
#pragma unroll
    for (int ni = 0; ni < 4; ni++) acc[mi][ni] = zero;

  const int ro = ((g ^ (r & 3) ^ ((r >> 2) & 3)) << 4);
  const int aOff = (wr * 128 + r) * 64 + ro;           // + mi*1024
  const int bOff = 16384 + (wc * 64 + r) * 64 + ro;    // + ni*1024

  SH(0, 0, 0); SH(0, 0, 1);

  for (int kt = 0; kt < KT; ++kt) {
    const int buf = kt & 1;
    const bool more = (kt + 1 < KT);
    const char* l0 = qsm + (buf * 2 + 0) * 32768;
    const char* l1 = qsm + (buf * 2 + 1) * 32768;

    asm volatile("s_waitcnt vmcnt(4)" ::: "memory");
    __builtin_amdgcn_s_barrier();
    __builtin_amdgcn_sched_barrier(0);
    s16x8 a[4], b[4];
#pragma unroll
    for (int ni = 0; ni < 4; ni++) b[ni] = *(const s16x8*)(l0 + bOff + ni * 1024);
#pragma unroll
    for (int i = 0; i < 4; i++) a[i] = *(const s16x8*)(l0 + aOff + i * 1024);
    if (more) SH(kt + 1, buf ^ 1, 0);
    __builtin_amdgcn_s_setprio(1);
#pragma unroll
    for (int ni = 0; ni < 4; ni++)
#pragma unroll
      for (int i = 0; i < 4; i++)
        acc[i][ni] = __builtin_amdgcn_mfma_f32_16x16x32_bf16(a[i], b[ni], acc[i][ni], 0, 0, 0);
    __builtin_amdgcn_s_setprio(0);

    s16x8 a2[4];
#pragma unroll
    for (int i = 0; i < 4; i++) a2[i] = *(const s16x8*)(l0 + aOff + (4 + i) * 1024);
    __builtin_amdgcn_s_setprio(1);
#pragma unroll
    for (int ni = 0; ni < 4; ni++)
#pragma unroll
      for (int i = 0; i < 4; i++)
        acc[4 + i][ni] = __builtin_amdgcn_mfma_f32_16x16x32_bf16(a2[i], b[ni], acc[4 + i][ni], 0, 0, 0);
    __builtin_amdgcn_s_setprio(0);

    if (more) { asm volatile("s_waitcnt vmcnt(4)" ::: "memory"); }
    else      { asm volatile("s_waitcnt vmcnt(0)" ::: "memory"); }
    __builtin_amdgcn_s_barrier();
    __builtin_amdgcn_sched_barrier(0);
#pragma unroll
    for (int ni = 0; ni < 4; ni++) b[ni] = *(const s16x8*)(l1 + bOff + ni * 1024);
#pragma unroll
    for (int i = 0; i < 4; i++) a[i] = *(const s16x8*)(l1 + aOff + i * 1024);
    if (more) SH(kt + 1, buf ^ 1, 1);
    __builtin_amdgcn_s_setprio(1);
#pragma unroll
    for (int ni = 0; ni < 4; ni++)
#pragma unroll
      for (int i = 0; i < 4; i++)
        acc[i][ni] = __builtin_amdgcn_mfma_f32_16x16x32_bf16(a[i], b[ni], acc[i][ni], 0, 0, 0);
    __builtin_amdgcn_s_setprio(0);

#pragma unroll
    for (int i = 0; i < 4; i++) a2[i] = *(const s16x8*)(l1 + aOff + (4 + i) * 1024);
    __builtin_amdgcn_s_setprio(1);
#pragma unroll
    for (int ni = 0; ni < 4; ni++)
#pragma unroll
      for (int i = 0; i < 4; i++)
        acc[4 + i][ni] = __builtin_amdgcn_mfma_f32_16x16x32_bf16(a2[i], b[ni], acc[4 + i][ni], 0, 0, 0);
    __builtin_amdgcn_s_setprio(0);
  }

#pragma unroll
  for (int mi = 0; mi < 8; mi++)
#pragma unroll
    for (int ni = 0; ni < 4; ni++) {
      const int crow = bm * 256 + wr * 128 + mi * 16 + g * 4;
      const int ccol = bn * 256 + wc * 64 + ni * 16 + r;
#pragma unroll
      for (int j = 0; j < 4; j++)
        store_out(&C[(size_t)(crow + j) * N + ccol], acc[mi][ni][j]);
    }
}
#undef SH

// ---------------- Triple-buffered counted-vmcnt GEMM ----------------
// VT_OUT: write C transposed into VT layout [bh*128+d][S_LEN] (V projection).
#define SA(kt, bi) {                                                           \
    const unsigned short* s_ = aS + (size_t)(kt) * 64;                         \
    char* d_ = (char*)Ab[bi] + tid * 16;                                       \
    GLL16(s_, d_);                                                             \
    GLL16(s_ + (size_t)64 * K, d_ + 8192);                                     \
  }
#define SB(kt, bi, hf) {                                                       \
    const unsigned short* s_ = bS + (size_t)(hf) * 128 * K + (size_t)(kt) * 64;\
    char* d_ = (char*)Bb[bi] + (hf) * 16384 + tid * 16;                        \
    GLL16(s_, d_);                                                             \
    GLL16(s_ + (size_t)64 * K, d_ + 8192);                                     \
  }

template <typename OutT, int NI, bool VT_OUT>
__global__ __launch_bounds__(512, 1) void gemm8_kernel(const unsigned short* __restrict__ A,
                                                       const unsigned short* __restrict__ B,
                                                       OutT* __restrict__ C, int K, int N) {
  __shared__ __align__(16) unsigned short Ab[3][128 * 64];       // 48 KB
  __shared__ __align__(16) unsigned short Bb[3][NI * 64 * 64];   // 96 or 48 KB
  const int bm = blockIdx.y, bn = blockIdx.x;                    // plain mapping
  const int tid = threadIdx.x;
  const int w = tid >> 6, wr = w >> 2, wc = w & 3;
  const int l = tid & 63, g = l >> 4, r = l & 15;
  const int KT = K >> 6;

  const int srow = tid >> 3;
  const int sgr = (tid & 7) ^ (srow & 7);
  const unsigned short* aS = A + (size_t)(bm * 128 + srow) * K + sgr * 8;
  const unsigned short* bS = B + (size_t)(bn * (NI * 64) + srow) * K + sgr * 8;

  f32x4 zero = {0.f, 0.f, 0.f, 0.f};
  f32x4 acc[4][NI];
#pragma unroll
  for (int mi = 0; mi < 4; mi++)
#pragma unroll
    for (int ni = 0; ni < NI; ni++) acc[mi][ni] = zero;

  const int swx = (r & 7) << 4;
  const int ks0 = (g << 4) ^ swx;
  const int ks1 = ((4 | g) << 4) ^ swx;
  const int aOff = (wr * 64 + r) * 128;
  const int bOff = (wc * (NI * 16) + r) * 128;

  SA(0, 0); SB(0, 0, 0); if (NI == 4) SB(0, 0, 1);
  SA(1, 1); SB(1, 1, 0); if (NI == 4) SB(1, 1, 1);

  int cur = 0;
  for (int kt = 0; kt < KT; ++kt) {
    const int b2 = (cur >= 1) ? cur - 1 : cur + 2;   // (cur+2)%3
    if (kt == KT - 1)      { asm volatile("s_waitcnt vmcnt(0)" ::: "memory"); }
    else if (NI == 4)      { asm volatile("s_waitcnt vmcnt(6)" ::: "memory"); }
    else                   { asm volatile("s_waitcnt vmcnt(4)" ::: "memory"); }
    __builtin_amdgcn_s_barrier();
    __builtin_amdgcn_sched_barrier(0);
    const char* lA = (const char*)Ab[cur];
    const char* lB = (const char*)Bb[cur];
    const bool more = (kt + 2 < KT);

    s16x8 a[4][2], b[NI][2];
#pragma unroll
    for (int mi = 0; mi < 4; mi++) {
      a[mi][0] = *(const s16x8*)(lA + aOff + mi * 2048 + ks0);
      a[mi][1] = *(const s16x8*)(lA + aOff + mi * 2048 + ks1);
    }
#pragma unroll
    for (int ni = 0; ni < NI / 2; ni++) {
      b[ni][0] = *(const s16x8*)(lB + bOff + ni * 2048 + ks0);
      b[ni][1] = *(const s16x8*)(lB + bOff + ni * 2048 + ks1);
    }
    if (more) { SA(kt + 2, b2); if (NI == 4) SB(kt + 2, b2, 0); }
    __builtin_amdgcn_s_setprio(1);
#pragma unroll
    for (int kk = 0; kk < 2; kk++)
#pragma unroll
      for (int ni = 0; ni < NI / 2; ni++)
#pragma unroll
        for (int mi = 0; mi < 4; mi++)
          acc[mi][ni] = __builtin_amdgcn_mfma_f32_16x16x32_bf16(a[mi][kk], b[ni][kk], acc[mi][ni], 0, 0, 0);
    __builtin_amdgcn_s_setprio(0);
    __builtin_amdgcn_sched_barrier(0);

#pragma unroll
    for (int ni = NI / 2; ni < NI; ni++) {
      b[ni][0] = *(const s16x8*)(lB + bOff + ni * 2048 + ks0);
      b[ni][1] = *(const s16x8*)(lB + bOff + ni * 2048 + ks1);
    }
    if (more) { if (NI == 4) { SB(kt + 2, b2, 1); } else { SB(kt + 2, b2, 0); } }
    __builtin_amdgcn_s_setprio(1);
#pragma unroll
    for (int kk = 0; kk < 2; kk++)
#pragma unroll
      for (int ni = NI / 2; ni < NI; ni++)
#pragma unroll
        for (int mi = 0; mi < 4; mi++)
          acc[mi][ni] = __builtin_amdgcn_mfma_f32_16x16x32_bf16(a[mi][kk], b[ni][kk], acc[mi][ni], 0, 0, 0);
    __builtin_amdgcn_s_setprio(0);
    cur = (cur == 2) ? 0 : cur + 1;
  }

#pragma unroll
  for (int mi = 0; mi < 4; mi++)
#pragma unroll
    for (int ni = 0; ni < NI; ni++) {
      const int crow = bm * 128 + wr * 64 + mi * 16 + g * 4;
      const int ccol = bn * (NI * 64) + wc * (NI * 16) + ni * 16 + r;
      if constexpr (VT_OUT) {
        // C^T into VT[(b*16+head)*128 + d][s]; 4 consecutive tokens -> ushort4
        const int bidx = crow >> 11;            // token / S_LEN
        const int s0 = crow & (S_LEN - 1);
        const int vrow = (bidx * 16 + (ccol >> 7)) * 128 + (ccol & 127);
        ushort4 o;
        o.x = f2bf(acc[mi][ni][0]); o.y = f2bf(acc[mi][ni][1]);
        o.z = f2bf(acc[mi][ni][2]); o.w = f2bf(acc[mi][ni][3]);
        *(ushort4*)((unsigned short*)C + (size_t)vrow * S_LEN + s0) = o;
      } else {
#pragma unroll
        for (int j = 0; j < 4; j++)
          store_out(&C[(size_t)(crow + j) * N + ccol], acc[mi][ni][j]);
      }
    }
}

// ---------------- Flash attention, causal, swapped-operand softmax ----------------
// (round-13 proven structure: 77us) 512 blocks x 256 thr (4 waves). Each block
// runs TWO sequential 64-row q-tile passes: qtA = 31-p then qtB = p -> constant
// 33 kv-tile iterations per block (dispatch-order-independent balance). KVBLK=64,
// LDS 72KB (2 blocks/CU), dbuf KV, STAGE(kt+1) right after top barrier, QK as
// mfma(K,Q) (lane holds S^T[kv][q=r]), exp2 domain, defer-max THR=8, cvt_pk
// P->LDS b64, PV = mfma(V^T,P^T), lane-partial l reduced in epilogue.
__global__ __launch_bounds__(256, 2) void attn_kernel(const unsigned short* __restrict__ QK,
                                                      const unsigned short* __restrict__ VT,
                                                      unsigned short* __restrict__ O) {
  __shared__ __align__(16) unsigned short Ksm[2][64 * 128];    // 32KB swizzled
  __shared__ __align__(16) unsigned short VTsm[2][128 * 64];   // 32KB swizzled
  __shared__ __align__(16) unsigned short Psm[4 * 16 * 64];    // 8KB per-wave [q][kv]
  const int bid = blockIdx.x;
  const int grp = bid & 7, idx = bid >> 3;     // idx 0..63
  const int p = idx >> 2;                      // 0..15
  const int bh = (grp << 2) | (idx & 3);
  const int b = bh >> 4, hd = bh & 15;
  const int tid = threadIdx.x, w = tid >> 6, l = tid & 63, g = l >> 4, r = l & 15;

  const int cK = tid & 15, rowK = tid >> 4;            // 0..15 (+16/i)
  const unsigned short* kp_base = QK + (size_t)(b * S_LEN + rowK) * QKS + HID + hd * HDIM
                                  + ((cK ^ (rowK & 7)) << 3);
  const int cV = tid & 7, dV = tid >> 3;               // 0..31 (+32/i)
  const unsigned short* vp_base = VT + (size_t)(bh * 128 + dV) * S_LEN + ((cV ^ (dV & 7)) << 3);
  char* const ksm0 = (char*)Ksm;
  char* const vtsm0 = (char*)VTsm;
  char* const psm_w = (char*)Psm + w * 2048;
  const int pswz = (r & 7) << 4;
  f32x4 zero = {0.f, 0.f, 0.f, 0.f};

#define STAGE(kt, bufi)                                                        \
  {                                                                            \
    const unsigned short* kp_ = kp_base + (size_t)((kt) * 64) * QKS;           \
    const unsigned short* vp_ = vp_base + (kt) * 64;                           \
    char* kd_ = ksm0 + (bufi) * 16384;                                         \
    char* vd_ = vtsm0 + (bufi) * 16384;                                        \
    GLL16(kp_,                      kd_ + tid * 16);                           \
    GLL16(kp_ + (size_t)16 * QKS,   kd_ + (tid + 256) * 16);                   \
    GLL16(kp_ + (size_t)32 * QKS,   kd_ + (tid + 512) * 16);                   \
    GLL16(kp_ + (size_t)48 * QKS,   kd_ + (tid + 768) * 16);                   \
    GLL16(vp_,                      vd_ + tid * 16);                           \
    GLL16(vp_ + (size_t)32 * S_LEN, vd_ + (tid + 256) * 16);                   \
    GLL16(vp_ + (size_t)64 * S_LEN, vd_ + (tid + 512) * 16);                   \
    GLL16(vp_ + (size_t)96 * S_LEN, vd_ + (tid + 768) * 16);                   \
  }

  for (int pass = 0; pass < 2; pass++) {
    const int qt = pass ? p : 31 - p;
    const int qbs = qt * 64 + w * 16;          // wave's q-row base (16 rows)

    // Q fragment (B operand): lane row = q = qbs + r (pre-scaled by scale*log2e)
    const unsigned short* qp = QK + (size_t)(b * S_LEN + qbs + r) * QKS + hd * HDIM;
    s16x8 qf[4];
#pragma unroll
    for (int ks = 0; ks < 4; ks++) qf[ks] = *(const s16x8*)(qp + ks * 32 + g * 8);

    float mreg = -1e30f, lregp = 0.f;          // lane-partial l
    f32x4 oacc[8];                             // O^T[d=di*16+g*4+jj][q=r]
#pragma unroll
    for (int di = 0; di < 8; di++) oacc[di] = zero;

    if (pass) __builtin_amdgcn_s_barrier();    // pass-1 readers done before overwrite
    const int nt = qt + 1;
    STAGE(0, 0);

    for (int kt2 = 0; kt2 < nt; kt2++) {
      const int buf = kt2 & 1;
      asm volatile("s_waitcnt vmcnt(0)" ::: "memory");
      __builtin_amdgcn_s_barrier();
      __builtin_amdgcn_sched_barrier(0);
      if (kt2 + 1 < nt) STAGE(kt2 + 1, buf ^ 1);   // flies under this tile's compute

      const char* ksm_c = ksm0 + buf * 16384;
      const char* vtsm_c = vtsm0 + buf * 16384;

      // S^T = K Q^T: sacc[ni][jj] = S[kv=kt2*64+ni*16+g*4+jj][q=qbs+r]
      f32x4 sacc[4];
#pragma unroll
      for (int ni = 0; ni < 4; ni++) sacc[ni] = zero;
#pragma unroll
      for (int ni = 0; ni < 4; ni++) {
        const int krow = ni * 16 + r;
        const int swz = (krow & 7) << 4;
        const char* kb2 = ksm_c + krow * 256;
#pragma unroll
        for (int ks = 0; ks < 4; ks++) {
          s16x8 kf = *(const s16x8*)(kb2 + ((ks * 64 + g * 16) ^ swz));
          sacc[ni] = __builtin_amdgcn_mfma_f32_16x16x32_bf16(kf, qf[ks], sacc[ni], 0, 0, 0);
        }
      }

      // causal mask (diagonal tile only)
      if (kt2 == qt) {
#pragma unroll
        for (int ni = 0; ni < 4; ni++)
#pragma unroll
          for (int jj = 0; jj < 4; jj++)
            if ((kt2 * 64 + ni * 16 + g * 4 + jj) > (qbs + r)) sacc[ni][jj] = -1e30f;
      }

      // row max for q=r: local 16-tree + 2 shfl (over g lanes)
      float m0 = fmaxf(fmaxf(sacc[0][0], sacc[0][1]), fmaxf(sacc[0][2], sacc[0][3]));
      float m1 = fmaxf(fmaxf(sacc[1][0], sacc[1][1]), fmaxf(sacc[1][2], sacc[1][3]));
      float m2 = fmaxf(fmaxf(sacc[2][0], sacc[2][1]), fmaxf(sacc[2][2], sacc[2][3]));
      float m3 = fmaxf(fmaxf(sacc[3][0], sacc[3][1]), fmaxf(sacc[3][2], sacc[3][3]));
      float mx = fmaxf(fmaxf(m0, m1), fmaxf(m2, m3));
      mx = fmaxf(mx, __shfl_xor(mx, 16, 64));
      mx = fmaxf(mx, __shfl_xor(mx, 32, 64));

      // defer-max (THR=8 in log2 units)
      if (__any(mx > mreg + 8.0f)) {
        float mn = fmaxf(mreg, mx);
        float corr = exp2f(mreg - mn);
        mreg = mn;
        lregp *= corr;
#pragma unroll
        for (int di = 0; di < 8; di++) oacc[di] = oacc[di] * corr;
      }

      // exp + lane-partial sum
#pragma unroll
      for (int ni = 0; ni < 4; ni++)
#pragma unroll
        for (int jj = 0; jj < 4; jj++) sacc[ni][jj] = exp2f(sacc[ni][jj] - mreg);
      float s0 = (sacc[0][0] + sacc[0][1]) + (sacc[0][2] + sacc[0][3]);
      float s1 = (sacc[1][0] + sacc[1][1]) + (sacc[1][2] + sacc[1][3]);
      float s2 = (sacc[2][0] + sacc[2][1]) + (sacc[2][2] + sacc[2][3]);
      float s3 = (sacc[3][0] + sacc[3][1]) + (sacc[3][2] + sacc[3][3]);
      lregp += (s0 + s1) + (s2 + s3);

      // P -> wave-private LDS [q=r][kv], swizzled; kv-pairs packed -> b64 writes
#pragma unroll
      for (int ni = 0; ni < 4; ni++) {
        unsigned int pk01, pk23;
        asm("v_cvt_pk_bf16_f32 %0, %1, %2" : "=v"(pk01) : "v"(sacc[ni][0]), "v"(sacc[ni][1]));
        asm("v_cvt_pk_bf16_f32 %0, %1, %2" : "=v"(pk23) : "v"(sacc[ni][2]), "v"(sacc[ni][3]));
        uint2 pk; pk.x = pk01; pk.y = pk23;
        *(uint2*)(psm_w + ((r * 128 + ni * 32 + g * 8) ^ pswz)) = pk;
      }

      // PV: O^T += V^T * P^T; A = V^T frag (row d), B = P^T frag (row q=r)
#pragma unroll
      for (int ksl = 0; ksl < 2; ksl++) {
        s16x8 pb = *(const s16x8*)(psm_w + ((r * 128 + ksl * 64 + g * 16) ^ pswz));
        const int kgran = ksl * 4 + g;
#pragma unroll
        for (int di = 0; di < 8; di++) {
          const int d = di * 16 + r;
          s16x8 vf = *(const s16x8*)(vtsm_c + d * 128 + ((kgran ^ (d & 7)) << 4));
          oacc[di] = __builtin_amdgcn_mfma_f32_16x16x32_bf16(vf, pb, oacc[di], 0, 0, 0);
        }
      }
    }

    // epilogue: reduce l across g lanes; O[q=qbs+r][d], 8B stores
    float lsum = lregp;
    lsum += __shfl_xor(lsum, 16, 64);
    lsum += __shfl_xor(lsum, 32, 64);
    const float inv = 1.0f / lsum;
    unsigned short* orow = O + (size_t)(b * S_LEN + qbs + r) * HID + hd * HDIM;
#pragma unroll
    for (int di = 0; di < 8; di++) {
      ushort4 o;
      o.x = f2bf(oacc[di][0] * inv); o.y = f2bf(oacc[di][1] * inv);
      o.z = f2bf(oacc[di][2] * inv); o.w = f2bf(oacc[di][3] * inv);
      *(ushort4*)(orow + di * 16 + g * 4) = o;
    }
  }
#undef STAGE
}

extern "C" void kernel_launch(void* const* d_in, const int* in_sizes, int n_in,
                              void* d_out, int out_size, void* d_ws, size_t ws_size,
                              hipStream_t stream) {
  const float* x      = (const float*)d_in[0];
  const float* norm_w = (const float*)d_in[1];
  const float* wq     = (const float*)d_in[2];
  const float* wk     = (const float*)d_in[3];
  const float* wv     = (const float*)d_in[4];
  const float* wo     = (const float*)d_in[5];
  const int*   pos    = (const int*)d_in[6];
  float* out = (float*)d_out;

  char* ws = (char*)d_ws;
  const size_t WQKV_B = (size_t)3 * HID * HID * 2;   // 24 MB
  const size_t WO_B   = (size_t)HID * HID * 2;       // 8 MB
  const size_t H_B    = (size_t)ROWS * HID * 2;      // 16 MB
  const size_t QK_B   = (size_t)ROWS * QKS * 2;      // 32 MB

  unsigned short* wqkvb = (unsigned short*)(ws);                     // [0,24)
  unsigned short* vt    = (unsigned short*)(ws);                     // aliases [0,16) after gemm_qk
  unsigned short* wob   = (unsigned short*)(ws + WQKV_B);            // [24,32)
  unsigned short* h     = (unsigned short*)(ws + WQKV_B + WO_B);     // [32,48) also ctx
  unsigned short* qk    = (unsigned short*)(ws + WQKV_B + WO_B + H_B);   // [48,80)
  float* ropetab = (float*)(ws + WQKV_B + WO_B + H_B + QK_B);        // S*64*2 fp32

  dim3 cgrid(HID * HID / 4 / 256, 4);
  cast4_kernel<<<cgrid, 256, 0, stream>>>(wq, wk, wv, wo, wqkvb, wob);
  rope_tab_kernel<<<S_LEN, 64, 0, stream>>>(ropetab);
  rmsnorm_kernel<<<ROWS, 256, 0, stream>>>(x, norm_w, h);

  // Q,K projection: 256x256-tile kernel, 16x16 = 256 blocks (1/CU, no tail)
  dim3 qkgrid(2 * HID / 256, ROWS / 256);
  gemm_qk_kernel<<<qkgrid, 512, 0, stream>>>(h, wqkvb, qk, HID, QKS);

  // V projection writes V^T directly (wq/wk region is dead after gemm_qk)
  dim3 vgrid(HID / 256, ROWS / 128);
  gemm8_kernel<unsigned short, 4, true><<<vgrid, 512, 0, stream>>>(
      h, wqkvb + (size_t)2 * HID * HID, vt, HID, S_LEN);

  rope_kernel<<<ROWS, 256, 0, stream>>>(pos, ropetab, qk);

  attn_kernel<<<512, 256, 0, stream>>>(qk, vt, h /* ctx */);

  // out-proj: gemm8 NI=4, 8x32 = 256 blocks
  dim3 ogrid(HID / 256, ROWS / 128);
  gemm8_kernel<float, 4, false><<<ogrid, 512, 0, stream>>>(h, wob, out, HID, HID);
}

// Round 16
// 251.534 us; speedup vs baseline: 1.3093x; 1.0167x over previous
//
#include <hip/hip_runtime.h>
#include <hip/hip_bf16.h>
#include <stdint.h>

#define S_LEN   2048
#define BATCH   2
#define HID     2048
#define NHEADS  16
#define HDIM    128
#define ROWS    (BATCH * S_LEN)          // 4096
#define QKS     4096                     // qk row stride (2*HID; V lives in VT)
#define ATT_SCALE 0.08838834764831843f   // 1/sqrt(128)
#define LOG2E     1.4426950408889634f
#define LOG2_10000 13.287712379549449f   // log2(10000)

typedef __attribute__((ext_vector_type(8))) short s16x8;
typedef __attribute__((ext_vector_type(4))) float f32x4;

#define GLL16(gp, lp)                                                          \
  __builtin_amdgcn_global_load_lds(                                            \
      (__attribute__((address_space(1))) void*)(gp),                           \
      (__attribute__((address_space(3))) void*)(lp), 16, 0, 0)

__device__ __forceinline__ float bf2f(unsigned short u) {
  union { unsigned int i; float f; } v; v.i = ((unsigned int)u) << 16; return v.f;
}
__device__ __forceinline__ unsigned short f2bf(float f) {
  union { float f; unsigned int i; } v; v.f = f;
  unsigned int i = v.i;
  return (unsigned short)((i + 0x7FFFu + ((i >> 16) & 1u)) >> 16);
}
__device__ __forceinline__ void store_out(unsigned short* p, float v) { *p = f2bf(v); }
__device__ __forceinline__ void store_out(float* p, float v) { *p = v; }
__device__ __forceinline__ float fmax3(float a, float b, float c) {
  return fmaxf(fmaxf(a, b), c);   // clang fuses to v_max3_f32
}

// ---------------- fused weight cast (4 weights) + rope table, 1 launch ----------------
__global__ __launch_bounds__(256) void cast5_kernel(const float* __restrict__ w0,
                                                    const float* __restrict__ w1,
                                                    const float* __restrict__ w2,
                                                    const float* __restrict__ w3,
                                                    unsigned short* __restrict__ dqkv,
                                                    unsigned short* __restrict__ dwo,
                                                    float* __restrict__ ropetab) {
  const int which = blockIdx.y;
  if (which == 4) {   // rope table: 2048 x-blocks x 64 lanes used
    int s = blockIdx.x, j = threadIdx.x;
    if (s < S_LEN && j < 64) {
      float inv = exp2f(-((float)j) * (LOG2_10000 / 64.0f));
      float ang = (float)s * inv;
      float2 cs;
      __sincosf(ang, &cs.y, &cs.x);       // cs.x = cos, cs.y = sin
      *(float2*)(ropetab + (s * 64 + j) * 2) = cs;
    }
    return;
  }
  const float* src = (which == 0) ? w0 : (which == 1) ? w1 : (which == 2) ? w2 : w3;
  unsigned short* dst = (which < 3) ? dqkv + (size_t)which * HID * HID : dwo;
  int i = blockIdx.x * 256 + threadIdx.x;
  float4 v = ((const float4*)src)[i];
  ushort4 o;
  o.x = f2bf(v.x); o.y = f2bf(v.y); o.z = f2bf(v.z); o.w = f2bf(v.w);
  ((ushort4*)dst)[i] = o;
}

// ---------------- RMSNorm (fp32 in, bf16 out) ----------------
__global__ __launch_bounds__(256) void rmsnorm_kernel(const float* __restrict__ x,
                                                      const float* __restrict__ w,
                                                      unsigned short* __restrict__ h) {
  int row = blockIdx.x;
  int t = threadIdx.x;
  const float4* xr4 = (const float4*)(x + (size_t)row * HID);
  float4 a = xr4[t], b = xr4[t + 256];
  float ss = a.x*a.x + a.y*a.y + a.z*a.z + a.w*a.w
           + b.x*b.x + b.y*b.y + b.z*b.z + b.w*b.w;
#pragma unroll
  for (int off = 32; off >= 1; off >>= 1) ss += __shfl_xor(ss, off, 64);
  __shared__ float red[4];
  if ((t & 63) == 0) red[t >> 6] = ss;
  __syncthreads();
  float tot = red[0] + red[1] + red[2] + red[3];
  float rs = rsqrtf(tot * (1.0f / (float)HID) + 1e-6f);
  const float4* w4 = (const float4*)w;
  float4 wa = w4[t], wb = w4[t + 256];
  ushort4 oa, ob;
  oa.x = f2bf(a.x * wa.x * rs); oa.y = f2bf(a.y * wa.y * rs);
  oa.z = f2bf(a.z * wa.z * rs); oa.w = f2bf(a.w * wa.w * rs);
  ob.x = f2bf(b.x * wb.x * rs); ob.y = f2bf(b.y * wb.y * rs);
  ob.z = f2bf(b.z * wb.z * rs); ob.w = f2bf(b.w * wb.w * rs);
  ushort4* hr = (ushort4*)(h + (size_t)row * HID);
  hr[t] = oa; hr[t + 256] = ob;
}

// ---------------- RoPE apply in-place on q,k (qk buffer, stride QKS) ----------------
// q pre-scaled by ATT_SCALE*log2(e): attention softmax runs in the exp2 domain.
__global__ __launch_bounds__(256) void rope_kernel(const int* __restrict__ pos_ids,
                                                   const float* __restrict__ tab,
                                                   unsigned short* __restrict__ qk) {
  int row = blockIdx.x;            // b*S + s
  int p = pos_ids[row];
  int t = threadIdx.x;
  int head = t >> 4;
  int j0 = (t & 15) * 4;
  size_t base = (size_t)row * QKS + head * HDIM;
  float4 cs01 = *(const float4*)(tab + (p * 64 + j0) * 2);      // c0 s0 c1 s1
  float4 cs23 = *(const float4*)(tab + (p * 64 + j0 + 2) * 2);  // c2 s2 c3 s3
  float4 c = {cs01.x, cs01.z, cs23.x, cs23.z};
  float4 s = {cs01.y, cs01.w, cs23.y, cs23.w};
#pragma unroll
  for (int which = 0; which < 2; which++) {
    unsigned short* ptr = qk + base + which * HID;  // q then k
    float sc = which ? 1.0f : (ATT_SCALE * LOG2E);
    ushort4 v1 = *(ushort4*)(ptr + j0);
    ushort4 v2 = *(ushort4*)(ptr + 64 + j0);
    ushort4 o1, o2;
    o1.x = f2bf((bf2f(v1.x) * c.x - bf2f(v2.x) * s.x) * sc);
    o1.y = f2bf((bf2f(v1.y) * c.y - bf2f(v2.y) * s.y) * sc);
    o1.z = f2bf((bf2f(v1.z) * c.z - bf2f(v2.z) * s.z) * sc);
    o1.w = f2bf((bf2f(v1.w) * c.w - bf2f(v2.w) * s.w) * sc);
    o2.x = f2bf((bf2f(v2.x) * c.x + bf2f(v1.x) * s.x) * sc);
    o2.y = f2bf((bf2f(v2.y) * c.y + bf2f(v1.y) * s.y) * sc);
    o2.z = f2bf((bf2f(v2.z) * c.z + bf2f(v1.z) * s.z) * sc);
    o2.w = f2bf((bf2f(v2.w) * c.w + bf2f(v1.w) * s.w) * sc);
    *(ushort4*)(ptr + j0) = o1;
    *(ushort4*)(ptr + 64 + j0) = o2;
  }
}

// ---------------- 256x256 kk-half-staggered GEMM (QK projection) ----------------
#define SH(kt, bi, kk2) {                                                      \
    const unsigned short* sa_ = aQ + (size_t)(kt) * 64 + (kk2) * 32;           \
    const unsigned short* sb_ = bQ + (size_t)(kt) * 64 + (kk2) * 32;           \
    char* da_ = qsm + ((bi) * 2 + (kk2)) * 32768 + tid * 16;                   \
    GLL16(sa_, da_);                                                           \
    GLL16(sa_ + (size_t)128 * K, da_ + 8192);                                  \
    GLL16(sb_, da_ + 16384);                                                   \
    GLL16(sb_ + (size_t)128 * K, da_ + 16384 + 8192);                          \
  }

__global__ __launch_bounds__(512, 2) void gemm_qk_kernel(const unsigned short* __restrict__ A,
                                                         const unsigned short* __restrict__ B,
                                                         unsigned short* __restrict__ C,
                                                         int K, int N) {
  __shared__ __align__(16) unsigned short Qsm[2][2][2][256 * 32];  // 128 KB
  const int bm = blockIdx.y, bn = blockIdx.x;
  const int tid = threadIdx.x;
  const int w = tid >> 6, wr = w >> 2, wc = w & 3;
  const int l = tid & 63, g = l >> 4, r = l & 15;
  const int KT = K >> 6;

  const int srow = tid >> 2;
  const int sg = (tid & 3) ^ ((tid >> 2) & 3) ^ ((tid >> 4) & 3);
  const unsigned short* aQ = A + (size_t)(bm * 256 + srow) * K + sg * 8;
  const unsigned short* bQ = B + (size_t)(bn * 256 + srow) * K + sg * 8;
  char* const qsm = (char*)Qsm;

  f32x4 zero = {0.f, 0.f, 0.f, 0.f};
  f32x4 acc[8][4];
#pragma unroll
  for (int mi = 0; mi < 8; mi++)
#pragma unroll
    for (int ni = 0; ni < 4; ni++) acc[mi][ni] = zero;

  const int ro = ((g ^ (r & 3) ^ ((r >> 2) & 3)) << 4);
  const int aOff = (wr * 128 + r) * 64 + ro;           // + mi*1024
  const int bOff = 16384 + (wc * 64 + r) * 64 + ro;    // + ni*1024

  SH(0, 0, 0); SH(0, 0, 1);

  for (int kt = 0; kt < KT; ++kt) {
    const int buf = kt & 1;
    const bool more = (kt + 1 < KT);
    const char* l0 = qsm + (buf * 2 + 0) * 32768;
    const char* l1 = qsm + (buf * 2 + 1) * 32768;

    asm volatile("s_waitcnt vmcnt(4)" ::: "memory");
    __builtin_amdgcn_s_barrier();
    __builtin_amdgcn_sched_barrier(0);
    s16x8 a[4], b[4];
#pragma unroll
    for (int ni = 0; ni < 4; ni++) b[ni] = *(const s16x8*)(l0 + bOff + ni * 1024);
#pragma unroll
    for (int i = 0; i < 4; i++) a[i] = *(const s16x8*)(l0 + aOff + i * 1024);
    if (more) SH(kt + 1, buf ^ 1, 0);
    __builtin_amdgcn_s_setprio(1);
#pragma unroll
    for (int ni = 0; ni < 4; ni++)
#pragma unroll
      for (int i = 0; i < 4; i++)
        acc[i][ni] = __builtin_amdgcn_mfma_f32_16x16x32_bf16(a[i], b[ni], acc[i][ni], 0, 0, 0);
    __builtin_amdgcn_s_setprio(0);

    s16x8 a2[4];
#pragma unroll
    for (int i = 0; i < 4; i++) a2[i] = *(const s16x8*)(l0 + aOff + (4 + i) * 1024);
    __builtin_amdgcn_s_setprio(1);
#pragma unroll
    for (int ni = 0; ni < 4; ni++)
#pragma unroll
      for (int i = 0; i < 4; i++)
        acc[4 + i][ni] = __builtin_amdgcn_mfma_f32_16x16x32_bf16(a2[i], b[ni], acc[4 + i][ni], 0, 0, 0);
    __builtin_amdgcn_s_setprio(0);

    if (more) { asm volatile("s_waitcnt vmcnt(4)" ::: "memory"); }
    else      { asm volatile("s_waitcnt vmcnt(0)" ::: "memory"); }
    __builtin_amdgcn_s_barrier();
    __builtin_amdgcn_sched_barrier(0);
#pragma unroll
    for (int ni = 0; ni < 4; ni++) b[ni] = *(const s16x8*)(l1 + bOff + ni * 1024);
#pragma unroll
    for (int i = 0; i < 4; i++) a[i] = *(const s16x8*)(l1 + aOff + i * 1024);
    if (more) SH(kt + 1, buf ^ 1, 1);
    __builtin_amdgcn_s_setprio(1);
#pragma unroll
    for (int ni = 0; ni < 4; ni++)
#pragma unroll
      for (int i = 0; i < 4; i++)
        acc[i][ni] = __builtin_amdgcn_mfma_f32_16x16x32_bf16(a[i], b[ni], acc[i][ni], 0, 0, 0);
    __builtin_amdgcn_s_setprio(0);

#pragma unroll
    for (int i = 0; i < 4; i++) a2[i] = *(const s16x8*)(l1 + aOff + (4 + i) * 1024);
    __builtin_amdgcn_s_setprio(1);
#pragma unroll
    for (int ni = 0; ni < 4; ni++)
#pragma unroll
      for (int i = 0; i < 4; i++)
        acc[4 + i][ni] = __builtin_amdgcn_mfma_f32_16x16x32_bf16(a2[i], b[ni], acc[4 + i][ni], 0, 0, 0);
    __builtin_amdgcn_s_setprio(0);
  }

#pragma unroll
  for (int mi = 0; mi < 8; mi++)
#pragma unroll
    for (int ni = 0; ni < 4; ni++) {
      const int crow = bm * 256 + wr * 128 + mi * 16 + g * 4;
      const int ccol = bn * 256 + wc * 64 + ni * 16 + r;
#pragma unroll
      for (int j = 0; j < 4; j++)
        store_out(&C[(size_t)(crow + j) * N + ccol], acc[mi][ni][j]);
    }
}
#undef SH

// ---------------- Triple-buffered counted-vmcnt GEMM ----------------
// VT_OUT: write C transposed into VT layout [bh*128+d][S_LEN] (V projection).
#define SA(kt, bi) {                                                           \
    const unsigned short* s_ = aS + (size_t)(kt) * 64;                         \
    char* d_ = (char*)Ab[bi] + tid * 16;                                       \
    GLL16(s_, d_);                                                             \
    GLL16(s_ + (size_t)64 * K, d_ + 8192);                                     \
  }
#define SB(kt, bi, hf) {                                                       \
    const unsigned short* s_ = bS + (size_t)(hf) * 128 * K + (size_t)(kt) * 64;\
    char* d_ = (char*)Bb[bi] + (hf) * 16384 + tid * 16;                        \
    GLL16(s_, d_);                                                             \
    GLL16(s_ + (size_t)64 * K, d_ + 8192);                                     \
  }

template <typename OutT, int NI, bool VT_OUT>
__global__ __launch_bounds__(512, 1) void gemm8_kernel(const unsigned short* __restrict__ A,
                                                       const unsigned short* __restrict__ B,
                                                       OutT* __restrict__ C, int K, int N) {
  __shared__ __align__(16) unsigned short Ab[3][128 * 64];       // 48 KB
  __shared__ __align__(16) unsigned short Bb[3][NI * 64 * 64];   // 96 or 48 KB
  const int bm = blockIdx.y, bn = blockIdx.x;                    // plain mapping
  const int tid = threadIdx.x;
  const int w = tid >> 6, wr = w >> 2, wc = w & 3;
  const int l = tid & 63, g = l >> 4, r = l & 15;
  const int KT = K >> 6;

  const int srow = tid >> 3;
  const int sgr = (tid & 7) ^ (srow & 7);
  const unsigned short* aS = A + (size_t)(bm * 128 + srow) * K + sgr * 8;
  const unsigned short* bS = B + (size_t)(bn * (NI * 64) + srow) * K + sgr * 8;

  f32x4 zero = {0.f, 0.f, 0.f, 0.f};
  f32x4 acc[4][NI];
#pragma unroll
  for (int mi = 0; mi < 4; mi++)
#pragma unroll
    for (int ni = 0; ni < NI; ni++) acc[mi][ni] = zero;

  const int swx = (r & 7) << 4;
  const int ks0 = (g << 4) ^ swx;
  const int ks1 = ((4 | g) << 4) ^ swx;
  const int aOff = (wr * 64 + r) * 128;
  const int bOff = (wc * (NI * 16) + r) * 128;

  SA(0, 0); SB(0, 0, 0); if (NI == 4) SB(0, 0, 1);
  SA(1, 1); SB(1, 1, 0); if (NI == 4) SB(1, 1, 1);

  int cur = 0;
  for (int kt = 0; kt < KT; ++kt) {
    const int b2 = (cur >= 1) ? cur - 1 : cur + 2;   // (cur+2)%3
    if (kt == KT - 1)      { asm volatile("s_waitcnt vmcnt(0)" ::: "memory"); }
    else if (NI == 4)      { asm volatile("s_waitcnt vmcnt(6)" ::: "memory"); }
    else                   { asm volatile("s_waitcnt vmcnt(4)" ::: "memory"); }
    __builtin_amdgcn_s_barrier();
    __builtin_amdgcn_sched_barrier(0);
    const char* lA = (const char*)Ab[cur];
    const char* lB = (const char*)Bb[cur];
    const bool more = (kt + 2 < KT);

    s16x8 a[4][2], b[NI][2];
#pragma unroll
    for (int mi = 0; mi < 4; mi++) {
      a[mi][0] = *(const s16x8*)(lA + aOff + mi * 2048 + ks0);
      a[mi][1] = *(const s16x8*)(lA + aOff + mi * 2048 + ks1);
    }
#pragma unroll
    for (int ni = 0; ni < NI / 2; ni++) {
      b[ni][0] = *(const s16x8*)(lB + bOff + ni * 2048 + ks0);
      b[ni][1] = *(const s16x8*)(lB + bOff + ni * 2048 + ks1);
    }
    if (more) { SA(kt + 2, b2); if (NI == 4) SB(kt + 2, b2, 0); }
    __builtin_amdgcn_s_setprio(1);
#pragma unroll
    for (int kk = 0; kk < 2; kk++)
#pragma unroll
      for (int ni = 0; ni < NI / 2; ni++)
#pragma unroll
        for (int mi = 0; mi < 4; mi++)
          acc[mi][ni] = __builtin_amdgcn_mfma_f32_16x16x32_bf16(a[mi][kk], b[ni][kk], acc[mi][ni], 0, 0, 0);
    __builtin_amdgcn_s_setprio(0);
    __builtin_amdgcn_sched_barrier(0);

#pragma unroll
    for (int ni = NI / 2; ni < NI; ni++) {
      b[ni][0] = *(const s16x8*)(lB + bOff + ni * 2048 + ks0);
      b[ni][1] = *(const s16x8*)(lB + bOff + ni * 2048 + ks1);
    }
    if (more) { if (NI == 4) { SB(kt + 2, b2, 1); } else { SB(kt + 2, b2, 0); } }
    __builtin_amdgcn_s_setprio(1);
#pragma unroll
    for (int kk = 0; kk < 2; kk++)
#pragma unroll
      for (int ni = NI / 2; ni < NI; ni++)
#pragma unroll
        for (int mi = 0; mi < 4; mi++)
          acc[mi][ni] = __builtin_amdgcn_mfma_f32_16x16x32_bf16(a[mi][kk], b[ni][kk], acc[mi][ni], 0, 0, 0);
    __builtin_amdgcn_s_setprio(0);
    cur = (cur == 2) ? 0 : cur + 1;
  }

#pragma unroll
  for (int mi = 0; mi < 4; mi++)
#pragma unroll
    for (int ni = 0; ni < NI; ni++) {
      const int crow = bm * 128 + wr * 64 + mi * 16 + g * 4;
      const int ccol = bn * (NI * 64) + wc * (NI * 16) + ni * 16 + r;
      if constexpr (VT_OUT) {
        // C^T into VT[(b*16+head)*128 + d][s]; 4 consecutive tokens -> ushort4
        const int bidx = crow >> 11;            // token / S_LEN
        const int s0 = crow & (S_LEN - 1);
        const int vrow = (bidx * 16 + (ccol >> 7)) * 128 + (ccol & 127);
        ushort4 o;
        o.x = f2bf(acc[mi][ni][0]); o.y = f2bf(acc[mi][ni][1]);
        o.z = f2bf(acc[mi][ni][2]); o.w = f2bf(acc[mi][ni][3]);
        *(ushort4*)((unsigned short*)C + (size_t)vrow * S_LEN + s0) = o;
      } else {
#pragma unroll
        for (int j = 0; j < 4; j++)
          store_out(&C[(size_t)(crow + j) * N + ccol], acc[mi][ni][j]);
      }
    }
}

// ---------------- Flash attention, causal, swapped-operand softmax ----------------
// r13 structure (77us) + strength-reduced LDS addressing (precomputed swizzled
// column offsets + immediate row offsets; targets the 36.8% VALUBusy) + v_max3
// tree. 512 blocks x 256 thr (4 waves), two passes qtA=31-p / qtB=p (constant
// 33 kv-tiles/block), KVBLK=64, LDS 72KB (2 blocks/CU), dbuf KV, exp2 domain,
// defer-max THR=8, cvt_pk P->LDS b64, PV = mfma(V^T,P^T).
__global__ __launch_bounds__(256, 2) void attn_kernel(const unsigned short* __restrict__ QK,
                                                      const unsigned short* __restrict__ VT,
                                                      unsigned short* __restrict__ O) {
  __shared__ __align__(16) unsigned short Ksm[2][64 * 128];    // 32KB swizzled
  __shared__ __align__(16) unsigned short VTsm[2][128 * 64];   // 32KB swizzled
  __shared__ __align__(16) unsigned short Psm[4 * 16 * 64];    // 8KB per-wave [q][kv]
  const int bid = blockIdx.x;
  const int grp = bid & 7, idx = bid >> 3;     // idx 0..63
  const int p = idx >> 2;                      // 0..15
  const int bh = (grp << 2) | (idx & 3);
  const int b = bh >> 4, hd = bh & 15;
  const int tid = threadIdx.x, w = tid >> 6, l = tid & 63, g = l >> 4, r = l & 15;

  const int cK = tid & 15, rowK = tid >> 4;            // 0..15 (+16/i)
  const unsigned short* kp_base = QK + (size_t)(b * S_LEN + rowK) * QKS + HID + hd * HDIM
                                  + ((cK ^ (rowK & 7)) << 3);
  const int cV = tid & 7, dV = tid >> 3;               // 0..31 (+32/i)
  const unsigned short* vp_base = VT + (size_t)(bh * 128 + dV) * S_LEN + ((cV ^ (dV & 7)) << 3);
  char* const ksm0 = (char*)Ksm;
  char* const vtsm0 = (char*)VTsm;
  const int sw8 = (r & 7) << 4;
  // precomputed swizzled column offsets (loop-invariant: (krow&7)==(r&7) etc.)
  int kc[4], pcw[4], pcr[2], vc[2];
#pragma unroll
  for (int ks = 0; ks < 4; ks++) kc[ks] = (ks * 64 + g * 16) ^ sw8;
#pragma unroll
  for (int ni = 0; ni < 4; ni++) pcw[ni] = (ni * 32 + g * 8) ^ sw8;
#pragma unroll
  for (int ksl = 0; ksl < 2; ksl++) {
    pcr[ksl] = (ksl * 64 + g * 16) ^ sw8;
    vc[ksl] = ((ksl * 4 + g) ^ (r & 7)) << 4;
  }
  char* const pT = (char*)Psm + w * 2048 + r * 128;    // P row base for q=r
  f32x4 zero = {0.f, 0.f, 0.f, 0.f};

#define STAGE(kt, bufi)                                                        \
  {                                                                            \
    const unsigned short* kp_ = kp_base + (size_t)((kt) * 64) * QKS;           \
    const unsigned short* vp_ = vp_base + (kt) * 64;                           \
    char* kd_ = ksm0 + (bufi) * 16384;                                         \
    char* vd_ = vtsm0 + (bufi) * 16384;                                        \
    GLL16(kp_,                      kd_ + tid * 16);                           \
    GLL16(kp_ + (size_t)16 * QKS,   kd_ + (tid + 256) * 16);                   \
    GLL16(kp_ + (size_t)32 * QKS,   kd_ + (tid + 512) * 16);                   \
    GLL16(kp_ + (size_t)48 * QKS,   kd_ + (tid + 768) * 16);                   \
    GLL16(vp_,                      vd_ + tid * 16);                           \
    GLL16(vp_ + (size_t)32 * S_LEN, vd_ + (tid + 256) * 16);                   \
    GLL16(vp_ + (size_t)64 * S_LEN, vd_ + (tid + 512) * 16);                   \
    GLL16(vp_ + (size_t)96 * S_LEN, vd_ + (tid + 768) * 16);                   \
  }

  for (int pass = 0; pass < 2; pass++) {
    const int qt = pass ? p : 31 - p;
    const int qbs = qt * 64 + w * 16;          // wave's q-row base (16 rows)

    // Q fragment (B operand): lane row = q = qbs + r (pre-scaled by scale*log2e)
    const unsigned short* qp = QK + (size_t)(b * S_LEN + qbs + r) * QKS + hd * HDIM;
    s16x8 qf[4];
#pragma unroll
    for (int ks = 0; ks < 4; ks++) qf[ks] = *(const s16x8*)(qp + ks * 32 + g * 8);

    float mreg = -1e30f, lregp = 0.f;          // lane-partial l
    f32x4 oacc[8];                             // O^T[d=di*16+g*4+jj][q=r]
#pragma unroll
    for (int di = 0; di < 8; di++) oacc[di] = zero;

    if (pass) __builtin_amdgcn_s_barrier();    // pass-1 readers done before overwrite
    const int nt = qt + 1;
    STAGE(0, 0);

    for (int kt2 = 0; kt2 < nt; kt2++) {
      const int buf = kt2 & 1;
      asm volatile("s_waitcnt vmcnt(0)" ::: "memory");
      __builtin_amdgcn_s_barrier();
      __builtin_amdgcn_sched_barrier(0);
      if (kt2 + 1 < nt) STAGE(kt2 + 1, buf ^ 1);   // flies under this tile's compute

      const char* kT = ksm0 + buf * 16384 + r * 256;   // K row base (krow=ni*16+r)
      const char* vT = vtsm0 + buf * 16384 + r * 128;  // V row base (d=di*16+r)

      // S^T = K Q^T: sacc[ni][jj] = S[kv=kt2*64+ni*16+g*4+jj][q=qbs+r]
      f32x4 sacc[4];
#pragma unroll
      for (int ni = 0; ni < 4; ni++) sacc[ni] = zero;
#pragma unroll
      for (int ks = 0; ks < 4; ks++) {
        const char* kp2 = kT + kc[ks];
#pragma unroll
        for (int ni = 0; ni < 4; ni++) {
          s16x8 kf = *(const s16x8*)(kp2 + ni * 4096);
          sacc[ni] = __builtin_amdgcn_mfma_f32_16x16x32_bf16(kf, qf[ks], sacc[ni], 0, 0, 0);
        }
      }

      // causal mask (diagonal tile only)
      if (kt2 == qt) {
        const int qg = qbs + r - kt2 * 64 - g * 4;     // kv_local > qg+... compare
#pragma unroll
        for (int ni = 0; ni < 4; ni++)
#pragma unroll
          for (int jj = 0; jj < 4; jj++)
            if ((ni * 16 + jj) > qg) sacc[ni][jj] = -1e30f;
      }

      // row max for q=r: v_max3 tree + 2 shfl (over g lanes)
      float ma = fmax3(fmax3(sacc[0][0], sacc[0][1], sacc[0][2]),
                       fmax3(sacc[0][3], sacc[1][0], sacc[1][1]),
                       fmax3(sacc[1][2], sacc[1][3], sacc[2][0]));
      float mb = fmax3(fmax3(sacc[2][1], sacc[2][2], sacc[2][3]),
                       fmax3(sacc[3][0], sacc[3][1], sacc[3][2]),
                       sacc[3][3]);
      float mx = fmaxf(ma, mb);
      mx = fmaxf(mx, __shfl_xor(mx, 16, 64));
      mx = fmaxf(mx, __shfl_xor(mx, 32, 64));

      // defer-max (THR=8 in log2 units)
      if (__any(mx > mreg + 8.0f)) {
        float mn = fmaxf(mreg, mx);
        float corr = exp2f(mreg - mn);
        mreg = mn;
        lregp *= corr;
#pragma unroll
        for (int di = 0; di < 8; di++) oacc[di] = oacc[di] * corr;
      }

      // exp + lane-partial sum
#pragma unroll
      for (int ni = 0; ni < 4; ni++)
#pragma unroll
        for (int jj = 0; jj < 4; jj++) sacc[ni][jj] = exp2f(sacc[ni][jj] - mreg);
      float s0 = (sacc[0][0] + sacc[0][1]) + (sacc[0][2] + sacc[0][3]);
      float s1 = (sacc[1][0] + sacc[1][1]) + (sacc[1][2] + sacc[1][3]);
      float s2 = (sacc[2][0] + sacc[2][1]) + (sacc[2][2] + sacc[2][3]);
      float s3 = (sacc[3][0] + sacc[3][1]) + (sacc[3][2] + sacc[3][3]);
      lregp += (s0 + s1) + (s2 + s3);

      // P -> wave-private LDS [q=r][kv], swizzled; kv-pairs packed -> b64 writes
#pragma unroll
      for (int ni = 0; ni < 4; ni++) {
        unsigned int pk01, pk23;
        asm("v_cvt_pk_bf16_f32 %0, %1, %2" : "=v"(pk01) : "v"(sacc[ni][0]), "v"(sacc[ni][1]));
        asm("v_cvt_pk_bf16_f32 %0, %1, %2" : "=v"(pk23) : "v"(sacc[ni][2]), "v"(sacc[ni][3]));
        uint2 pk; pk.x = pk01; pk.y = pk23;
        *(uint2*)(pT + pcw[ni]) = pk;
      }

      // PV: O^T += V^T * P^T; A = V^T frag (row d), B = P^T frag (row q=r)
#pragma unroll
      for (int ksl = 0; ksl < 2; ksl++) {
        s16x8 pb = *(const s16x8*)(pT + pcr[ksl]);
        const char* vp2 = vT + vc[ksl];
#pragma unroll
        for (int di = 0; di < 8; di++) {
          s16x8 vf = *(const s16x8*)(vp2 + di * 2048);
          oacc[di] = __builtin_amdgcn_mfma_f32_16x16x32_bf16(vf, pb, oacc[di], 0, 0, 0);
        }
      }
    }

    // epilogue: reduce l across g lanes; O[q=qbs+r][d], 8B stores
    float lsum = lregp;
    lsum += __shfl_xor(lsum, 16, 64);
    lsum += __shfl_xor(lsum, 32, 64);
    const float inv = 1.0f / lsum;
    unsigned short* orow = O + (size_t)(b * S_LEN + qbs + r) * HID + hd * HDIM;
#pragma unroll
    for (int di = 0; di < 8; di++) {
      ushort4 o;
      o.x = f2bf(oacc[di][0] * inv); o.y = f2bf(oacc[di][1] * inv);
      o.z = f2bf(oacc[di][2] * inv); o.w = f2bf(oacc[di][3] * inv);
      *(ushort4*)(orow + di * 16 + g * 4) = o;
    }
  }
#undef STAGE
}

extern "C" void kernel_launch(void* const* d_in, const int* in_sizes, int n_in,
                              void* d_out, int out_size, void* d_ws, size_t ws_size,
                              hipStream_t stream) {
  const float* x      = (const float*)d_in[0];
  const float* norm_w = (const float*)d_in[1];
  const float* wq     = (const float*)d_in[2];
  const float* wk     = (const float*)d_in[3];
  const float* wv     = (const float*)d_in[4];
  const float* wo     = (const float*)d_in[5];
  const int*   pos    = (const int*)d_in[6];
  float* out = (float*)d_out;

  char* ws = (char*)d_ws;
  const size_t WQKV_B = (size_t)3 * HID * HID * 2;   // 24 MB
  const size_t WO_B   = (size_t)HID * HID * 2;       // 8 MB
  const size_t H_B    = (size_t)ROWS * HID * 2;      // 16 MB
  const size_t QK_B   = (size_t)ROWS * QKS * 2;      // 32 MB

  unsigned short* wqkvb = (unsigned short*)(ws);                     // [0,24)
  unsigned short* vt    = (unsigned short*)(ws);                     // aliases [0,16) after gemm_qk
  unsigned short* wob   = (unsigned short*)(ws + WQKV_B);            // [24,32)
  unsigned short* h     = (unsigned short*)(ws + WQKV_B + WO_B);     // [32,48) also ctx
  unsigned short* qk    = (unsigned short*)(ws + WQKV_B + WO_B + H_B);   // [48,80)
  float* ropetab = (float*)(ws + WQKV_B + WO_B + H_B + QK_B);        // S*64*2 fp32

  dim3 cgrid(HID * HID / 4 / 256, 5);
  cast5_kernel<<<cgrid, 256, 0, stream>>>(wq, wk, wv, wo, wqkvb, wob, ropetab);
  rmsnorm_kernel<<<ROWS, 256, 0, stream>>>(x, norm_w, h);

  // Q,K projection: 256x256-tile kernel, 16x16 = 256 blocks (1/CU, no tail)
  dim3 qkgrid(2 * HID / 256, ROWS / 256);
  gemm_qk_kernel<<<qkgrid, 512, 0, stream>>>(h, wqkvb, qk, HID, QKS);

  // V projection writes V^T directly (wq/wk region is dead after gemm_qk)
  dim3 vgrid(HID / 256, ROWS / 128);
  gemm8_kernel<unsigned short, 4, true><<<vgrid, 512, 0, stream>>>(
      h, wqkvb + (size_t)2 * HID * HID, vt, HID, S_LEN);

  rope_kernel<<<ROWS, 256, 0, stream>>>(pos, ropetab, qk);

  attn_kernel<<<512, 256, 0, stream>>>(qk, vt, h /* ctx */);

  // out-proj: gemm8 NI=4, 8x32 = 256 blocks
  dim3 ogrid(HID / 256, ROWS / 128);
  gemm8_kernel<float, 4, false><<<ogrid, 512, 0, stream>>>(h, wob, out, HID, HID);
}